// Round 8
// baseline (1311.339 us; speedup 1.0000x reference)
//
#include <hip/hip_runtime.h>
#include <math.h>

#define BB 4
#define NN 2048
#define KK 20
#define NEG 0.2f

// d_out layout: sim(4) q1(3200) q2(3200) e1(40) e2(40) xd1(3200) = 9684
#define QOFF0 4
#define QOFF1 3204
#define EOFF0 6404
#define EOFF1 6444
#define XDOFF 6484

typedef unsigned short u16;
typedef unsigned int u32;
typedef __attribute__((ext_vector_type(8))) short s16x8;     // 8 bf16 = 4 VGPR
typedef __attribute__((ext_vector_type(4))) float f32x4;     // 16x16 acc
typedef __attribute__((ext_vector_type(16))) float f32x16;   // 32x32 acc
typedef __attribute__((ext_vector_type(8))) u16 u16x8;

// ---------------- fp32 -> bf16 (round-nearest-even) ----------------
__device__ __forceinline__ u16 f2bf(float x) {
    u32 u = __float_as_uint(x);
    u += 0x7FFFu + ((u >> 16) & 1u);
    return (u16)(u >> 16);
}

// ------- transpose x (B,3,N) -> (B,N,3) + norms + padded bf16 planes -------
__global__ __launch_bounds__(256) void transpose_x_kernel(
    const float* __restrict__ x, float* __restrict__ fnc, float* __restrict__ xx,
    u16* __restrict__ fh, u16* __restrict__ fl)
{
    int gid = blockIdx.x * 256 + threadIdx.x;   // B*N = 8192
    int b = gid >> 11, n = gid & 2047;
    float s = 0.f;
    float v[3];
#pragma unroll
    for (int c = 0; c < 3; ++c) {
        v[c] = x[((size_t)b * 3 + c) * NN + n];
        fnc[(size_t)gid * 3 + c] = v[c];
        s += v[c] * v[c];
    }
    xx[gid] = s;
    u16x8 z = {0,0,0,0,0,0,0,0};
    u16x8 h0 = z, l0 = z;
#pragma unroll
    for (int c = 0; c < 3; ++c) {
        u16 hb = f2bf(v[c]);
        h0[c] = hb;
        l0[c] = f2bf(v[c] - __uint_as_float((u32)hb << 16));
    }
    u16* fhp = fh + (size_t)gid * 32;
    u16* flp = fl + (size_t)gid * 32;
    *(u16x8*)(fhp)      = h0; *(u16x8*)(fhp + 8)  = z;
    *(u16x8*)(fhp + 16) = z;  *(u16x8*)(fhp + 24) = z;
    *(u16x8*)(flp)      = l0; *(u16x8*)(flp + 8)  = z;
    *(u16x8*)(flp + 16) = z;  *(u16x8*)(flp + 24) = z;
}

// ---------------- row norms of a h512 channel slice ----------------
__global__ __launch_bounds__(256) void norms_kernel(
    const float* __restrict__ h512, int choff, int C, float* __restrict__ xx)
{
    int gid = blockIdx.x * 256 + threadIdx.x;   // 8192
    const float* p = h512 + (size_t)gid * 512 + choff;
    float s = 0.f;
    for (int c = 0; c < C; ++c) { float v = p[c]; s += v * v; }
    xx[gid] = s;
}

#define NINFV -3.4e38f

// ---- DPP pair-max step: merge sorted pair (a1>=a2) with lane-shifted copy.
template<int CTRL>
__device__ __forceinline__ void dmax2(float& a1, float& a2)
{
    int b1i = __builtin_amdgcn_update_dpp(
        __float_as_int(a1), __float_as_int(a1), CTRL, 0xf, 0xf, false);
    int b2i = __builtin_amdgcn_update_dpp(
        __float_as_int(a2), __float_as_int(a2), CTRL, 0xf, 0xf, false);
    float b1 = __int_as_float(b1i), b2 = __int_as_float(b2i);
    float n1 = fmaxf(a1, b1);
    float n2 = fmaxf(fminf(a1, b1), fmaxf(a2, b2));
    a1 = n1; a2 = n2;
}

// ============ async global->LDS (16B per lane, wave-uniform dest) ============
__device__ __forceinline__ void gload_lds16(const void* g, void* l) {
    __builtin_amdgcn_global_load_lds(
        (const __attribute__((address_space(1))) void*)g,
        (__attribute__((address_space(3))) void*)l, 16, 0, 0);
}

// ---------------- MFMA pairwise-dot -> global f32 scores ----------------
// 2 batches/dispatch, 16 rows/block, 512 thr (8 waves). Each wave owns a
// private 16-col strip per 128-col tile: stages it via global_load_lds
// (coalesced 16B, inverse-swizzled source), wave-local vmcnt(0) (no
// barriers), then 16x16x32 bf16-split MFMA (frag semantics identical to
// the r7-verified kernel). Scores stream to S (row-major, 64B segments).
template<int KT>   // number of 32-ch K-tiles; C = 32*KT
__global__ __launch_bounds__(512) void knn_dotg_kernel(
    const u16* __restrict__ Fh, const u16* __restrict__ Fl,
    int ncs, int choff, int bbase,
    const float* __restrict__ xx, float* __restrict__ S)
{
    __shared__ u16 Bst[8][2][KT][512];   // per-wave strip: [plane][kt][16col x 32ch]
    int tid = threadIdx.x;
    int bid = blockIdx.x;                // 256 = 2 batches x 128 row-tiles
    int bl  = bid & 1, b = bbase + bl;
    int r0  = (bid >> 1) << 4;
    int wv = tid >> 6, lane = tid & 63;
    int l15 = lane & 15, l4 = lane >> 4;

    // A fragments: rows r0..r0+15 (shared by all waves), scattered but tiny
    const u16* Ah0 = Fh + (size_t)(b * NN + r0 + l15) * ncs + choff + l4 * 8;
    const u16* Al0 = Fl + (size_t)(b * NN + r0 + l15) * ncs + choff + l4 * 8;
    s16x8 a_h[KT], a_l[KT];
#pragma unroll
    for (int kt = 0; kt < KT; ++kt) {
        a_h[kt] = *(const s16x8*)(Ah0 + kt * 32);
        a_l[kt] = *(const s16x8*)(Al0 + kt * 32);
    }

    int srow = lane >> 2;                 // col within wave strip (0..15)
    int scc  = (lane & 3) ^ (srow & 3);   // inverse-swizzled source chunk
    const float* xb = xx + b * NN;
    float* Sb = S + (size_t)bl * NN * NN;

    for (int t = 0; t < 16; ++t) {
        int c0 = (t << 7) + (wv << 4);    // wave's 16-col strip
        size_t srcrow = (size_t)(b * NN + c0 + srow) * ncs + choff;
#pragma unroll
        for (int kt = 0; kt < KT; ++kt) {
            gload_lds16(Fh + srcrow + kt * 32 + scc * 8, &Bst[wv][0][kt][0]);
            gload_lds16(Fl + srcrow + kt * 32 + scc * 8, &Bst[wv][1][kt][0]);
        }
        asm volatile("s_waitcnt vmcnt(0)" ::: "memory");

        f32x4 acc;
#pragma unroll
        for (int i = 0; i < 4; ++i) acc[i] = 0.f;
        int rb = l15 * 32 + ((l4 ^ (l15 & 3)) << 3);   // swizzled frag addr
#pragma unroll
        for (int kt = 0; kt < KT; ++kt) {
            s16x8 bh  = *(const s16x8*)&Bst[wv][0][kt][rb];
            s16x8 bl_ = *(const s16x8*)&Bst[wv][1][kt][rb];
            acc = __builtin_amdgcn_mfma_f32_16x16x32_bf16(a_h[kt], bh,  acc, 0, 0, 0);
            acc = __builtin_amdgcn_mfma_f32_16x16x32_bf16(a_l[kt], bh,  acc, 0, 0, 0);
            acc = __builtin_amdgcn_mfma_f32_16x16x32_bf16(a_h[kt], bl_, acc, 0, 0, 0);
        }
        float xv = xb[c0 + l15];
#pragma unroll
        for (int i = 0; i < 4; ++i)
            Sb[(size_t)(r0 + l4 * 4 + i) * NN + c0 + l15] = 2.f * acc[i] - xv;
    }
}

// ---------------- top-20 select from global scores ----------------
// 1 row/wave, 4 waves/block, NO LDS -> 32 waves/CU. rv register-resident
// (r3-proven, ~52 VGPR). Pair-pop DPP reduction (r6 logic verbatim).
__global__ __launch_bounds__(256) void knn_selg_kernel(
    const float* __restrict__ S, int bbase, int* __restrict__ idxout)
{
    int tid = threadIdx.x;
    int w = tid >> 6, lane = tid & 63;
    int row = blockIdx.x * 4 + w;        // 0..4095 (2 batches)
    int bl = row >> 11, n = row & 2047;
    const float* sb = S + ((size_t)bl * NN + n) * NN;
    int* op = idxout + ((size_t)((bbase + bl) * NN + n)) * KK;

    float rv[32];
#pragma unroll
    for (int j = 0; j < 32; ++j) {
        float vv = sb[lane + (j << 6)];
        rv[j] = (lane + (j << 6) == n) ? NINFV : vv;
    }
    if (lane == 0) op[0] = n;            // self is provably the max score

    // per-lane top-4 cache (compile-time-indexed register scans only)
    float v1 = NINFV, v2 = NINFV, v3 = NINFV, v4 = NINFV;
    int j1 = -1, j2 = -1, j3 = -1, j4 = -1;
#pragma unroll
    for (int j = 0; j < 32; ++j) {
        float vv = rv[j];
        if (vv > v1) { v4 = v3; j4 = j3; v3 = v2; j3 = j2; v2 = v1; j2 = j1; v1 = vv; j1 = j; }
        else if (vv > v2) { v4 = v3; j4 = j3; v3 = v2; j3 = j2; v2 = vv; j2 = j; }
        else if (vv > v3) { v4 = v3; j4 = j3; v3 = vv; j3 = j; }
        else if (vv > v4) { v4 = vv; j4 = j; }
    }

    unsigned consumed = 0u;

    for (int it = 1; it < KK; it += 2) {
        float r1 = v1, r2 = v2;
        dmax2<0x111>(r1, r2);
        dmax2<0x112>(r1, r2);
        dmax2<0x114>(r1, r2);
        dmax2<0x118>(r1, r2);
        dmax2<0x142>(r1, r2);
        dmax2<0x143>(r1, r2);
        float m1 = __int_as_float(
            __builtin_amdgcn_readlane(__float_as_int(r1), 63));
        float m2 = __int_as_float(
            __builtin_amdgcn_readlane(__float_as_int(r2), 63));
        unsigned long long k1 = __ballot(v1 == m1);
        if (lane == __ffsll(k1) - 1) {
            op[it] = lane + (j1 << 6);
            consumed |= 1u << j1;
            v1 = v2; j1 = j2; v2 = v3; j2 = j3; v3 = v4; j3 = j4;
            v4 = NINFV; j4 = -1;
        }
        if (it + 1 < KK) {
            unsigned long long k2 = __ballot(v1 == m2);
            if (lane == __ffsll(k2) - 1) {
                op[it + 1] = lane + (j1 << 6);
                consumed |= 1u << j1;
                v1 = v2; j1 = j2; v2 = v3; j2 = j3; v3 = v4; j3 = j4;
                v4 = NINFV; j4 = -1;
            }
        }
        if (__any(v2 == NINFV)) {
            if (v2 == NINFV) {           // rare: rebuild top-4 from registers
                v1 = NINFV; v2 = NINFV; v3 = NINFV; v4 = NINFV;
                j1 = -1; j2 = -1; j3 = -1; j4 = -1;
#pragma unroll
                for (int j = 0; j < 32; ++j) {
                    if (!(consumed & (1u << j))) {
                        float vv = rv[j];
                        if (vv > v1) { v4 = v3; j4 = j3; v3 = v2; j3 = j2; v2 = v1; j2 = j1; v1 = vv; j1 = j; }
                        else if (vv > v2) { v4 = v3; j4 = j3; v3 = v2; j3 = j2; v2 = vv; j2 = j; }
                        else if (vv > v3) { v4 = v3; j4 = j3; v3 = vv; j3 = j; }
                        else if (vv > v4) { v4 = vv; j4 = j; }
                    }
                }
            }
        }
    }
}

// ---------------- G = F*W1^T, H = F*(W2-W1)^T  (out layout (B*N, COUT)) ----
template<int C, int COUT>
__global__ __launch_bounds__(256) void gemm_gh_kernel(
    const float* __restrict__ fnc, int ncs, int choff,
    const float* __restrict__ W,     // (COUT, 2C)
    float* __restrict__ G, float* __restrict__ H)
{
    constexpr int GROUPS = 256 / COUT;
    constexpr int RPT = 8 / GROUPS;
    __shared__ float Fs[8][C];
    int tid = threadIdx.x;
    int row0 = blockIdx.x * 8;        // grid = B*N/8 = 1024
    for (int i = tid; i < 8 * C; i += 256) {
        int r = i / C, c = i % C;
        Fs[r][c] = fnc[(size_t)(row0 + r) * ncs + choff + c];
    }
    __syncthreads();
    int o = tid % COUT;
    int r0 = (tid / COUT) * RPT;
    float g[RPT], h[RPT];
#pragma unroll
    for (int r = 0; r < RPT; ++r) { g[r] = 0.f; h[r] = 0.f; }
    const float* wr = W + (size_t)o * 2 * C;
    for (int c = 0; c < C; ++c) {
        float w1 = wr[c], wd = wr[C + c] - w1;
#pragma unroll
        for (int r = 0; r < RPT; ++r) {
            float f = Fs[r0 + r][c];
            g[r] += f * w1; h[r] += f * wd;
        }
    }
#pragma unroll
    for (int r = 0; r < RPT; ++r) {
        size_t rr = (size_t)(row0 + r0 + r) * COUT + o;
        G[rr] = g[r]; H[rr] = h[r];
    }
}

// ---------------- gather y=G[m]+H[n]; max/min over k; BN stat partials -----
template<int COUT>
__global__ __launch_bounds__(256) void gather_kernel(
    const float* __restrict__ G, const float* __restrict__ H,
    const int* __restrict__ idx,
    float* __restrict__ ymax, float* __restrict__ ymin,
    float* __restrict__ psum, float* __restrict__ psumsq)
{
    constexpr int RPI = 256 / COUT;
    constexpr int NITER = 16 / RPI;
    int tid = threadIdx.x;
    int o = tid % COUT;
    int rsub = tid / COUT;
    int row0 = blockIdx.x * 16;       // grid = 512
    float s = 0.f, s2 = 0.f;
    for (int it = 0; it < NITER; ++it) {
        int r = row0 + it * RPI + rsub;
        int b = r >> 11;
        float h = H[(size_t)r * COUT + o];
        const int* ip = idx + (size_t)r * KK;
        float mx = -3.4e38f, mn = 3.4e38f;
#pragma unroll
        for (int j = 0; j < KK; ++j) {
            int m = ip[j];
            float g = G[((size_t)(b << 11) + m) * COUT + o];
            float y = g + h;
            mx = fmaxf(mx, y); mn = fminf(mn, y);
            s += y; s2 += y * y;
        }
        ymax[(size_t)r * COUT + o] = mx;
        ymin[(size_t)r * COUT + o] = mn;
    }
    __shared__ float ls[256], ls2[256];
    ls[tid] = s; ls2[tid] = s2;
    __syncthreads();
    for (int st = 128; st >= COUT; st >>= 1) {
        if (tid < st) { ls[tid] += ls[tid + st]; ls2[tid] += ls2[tid + st]; }
        __syncthreads();
    }
    if (tid < COUT) {
        psum[(size_t)blockIdx.x * COUT + tid]   = ls[tid];
        psumsq[(size_t)blockIdx.x * COUT + tid] = ls2[tid];
    }
}

// ---------------- finalize BN scale/shift: one block per channel ----------
__global__ __launch_bounds__(256) void bnscale_kernel(
    const float* __restrict__ psum, const float* __restrict__ psumsq,
    int nblk, int cout, float cnt,
    const float* __restrict__ gw, const float* __restrict__ bw,
    float* __restrict__ ss)
{
    int o = blockIdx.x;               // grid = cout
    int t = threadIdx.x;
    float s = 0.f, s2 = 0.f;
    for (int i = t; i < nblk; i += 256) {
        s  += psum[(size_t)i * cout + o];
        s2 += psumsq[(size_t)i * cout + o];
    }
    __shared__ float ls[256], ls2[256];
    ls[t] = s; ls2[t] = s2;
    __syncthreads();
    for (int st = 128; st > 0; st >>= 1) {
        if (t < st) { ls[t] += ls[t + st]; ls2[t] += ls2[t + st]; }
        __syncthreads();
    }
    if (t == 0) {
        float m = ls[0] / cnt;
        float v = ls2[0] / cnt - m * m;
        float sc = gw[o] / sqrtf(v + 1e-5f);
        float sh = bw[o] - m * sc;
        ss[o * 2] = sc; ss[o * 2 + 1] = sh;
    }
}

// ------- BN+LeakyReLU on max/min, elementwise + bf16 hi/lo emission -------
__global__ __launch_bounds__(256) void apply_kernel(
    const float* __restrict__ ymax, const float* __restrict__ ymin,
    const float* __restrict__ ss, int coutShift, int choff,
    float* __restrict__ h512, u16* __restrict__ Ah, u16* __restrict__ Al)
{
    size_t gid = (size_t)blockIdx.x * 256 + threadIdx.x;
    int o = (int)(gid & ((1u << coutShift) - 1));
    size_t r = gid >> coutShift;
    float sc = ss[o * 2], sh = ss[o * 2 + 1];
    float v = (sc >= 0.f) ? ymax[gid] : ymin[gid];
    float a = sc * v + sh;
    float act = (a > 0.f) ? a : NEG * a;
    size_t hidx = r * 512 + choff + o;
    h512[hidx] = act;
    u16 hb = f2bf(act);
    Ah[hidx] = hb;
    Al[hidx] = f2bf(act - __uint_as_float((u32)hb << 16));
}

// ---- BN+LeakyReLU + coalesced transposed fcn write + bf16 hi/lo ----------
template<int CO>
__global__ __launch_bounds__(256) void apply_t_kernel(
    const float* __restrict__ ymax, const float* __restrict__ ymin,
    const float* __restrict__ ss, int choff,
    float* __restrict__ h512, float* __restrict__ fcn,
    u16* __restrict__ Ah, u16* __restrict__ Al)
{
    constexpr int TILES_O = CO >> 6;
    __shared__ float tile[64][65];
    int tr = blockIdx.x / TILES_O;    // row tile 0..127
    int to = blockIdx.x % TILES_O;
    int r0 = tr * 64, o0 = to * 64;
    int t = threadIdx.x;
    int lr = t >> 6;                  // 0..3
    int lo = t & 63;
    int o = o0 + lo;
    float sc = ss[o * 2], sh = ss[o * 2 + 1];
#pragma unroll
    for (int rr = 0; rr < 64; rr += 4) {
        int r = r0 + rr + lr;
        size_t gid = (size_t)r * CO + o;
        float v = (sc >= 0.f) ? ymax[gid] : ymin[gid];
        float a = sc * v + sh;
        float act = (a > 0.f) ? a : NEG * a;
        size_t hidx = (size_t)r * 512 + choff + o;
        h512[hidx] = act;
        u16 hb = f2bf(act);
        Ah[hidx] = hb;
        Al[hidx] = f2bf(act - __uint_as_float((u32)hb << 16));
        tile[rr + lr][lo] = act;
    }
    __syncthreads();
    int b = r0 >> 11;
    int n0 = r0 & 2047;
#pragma unroll
    for (int oo = 0; oo < 64; oo += 4) {
        fcn[((size_t)(b * CO + o0 + oo + lr)) * NN + n0 + lo] = tile[lo][oo + lr];
    }
}

// ---------------- fp32 -> (hi, lo) bf16 split for w5 only ----------------
__global__ __launch_bounds__(256) void tobf16_b_kernel(
    const float* __restrict__ Bm, u16* __restrict__ Bh, u16* __restrict__ Bl)
{
    int gid = blockIdx.x * 256 + threadIdx.x;   // 65536 (1024*512/8)
    size_t off = (size_t)gid * 8;
    float4 v0 = *(const float4*)(Bm + off);
    float4 v1 = *(const float4*)(Bm + off + 4);
    float x[8] = {v0.x, v0.y, v0.z, v0.w, v1.x, v1.y, v1.z, v1.w};
    u16x8 h, l;
#pragma unroll
    for (int j = 0; j < 8; ++j) {
        u16 hb = f2bf(x[j]);
        h[j] = hb;
        l[j] = f2bf(x[j] - __uint_as_float((u32)hb << 16));
    }
    *(u16x8*)(Bh + off) = h;
    *(u16x8*)(Bl + off) = l;
}

// ============ conv1d GEMM via bf16x2-split MFMA (32x32x16) ============
__global__ __launch_bounds__(256) void gemm5_mfma_kernel(
    const u16* __restrict__ Ah, const u16* __restrict__ Al,
    const u16* __restrict__ Bh, const u16* __restrict__ Bl,
    float* __restrict__ Y, float* __restrict__ psum, float* __restrict__ psumsq)
{
    __shared__ u16 As[2][128][64];   // [plane][row][k] 32 KB
    __shared__ u16 Bs[2][128][64];   // 32 KB
    __shared__ float scs[4][128];
    __shared__ float sqs[4][128];

    int tid = threadIdx.x;
    int bm = blockIdx.x & 63, bn = blockIdx.x >> 6;
    int row0 = bm * 128, col0 = bn * 128;
    int w = tid >> 6, lane = tid & 63;
    int wr = w >> 1, wc = w & 1;

    int isB = w >> 1, plane = w & 1;
    int srow = lane >> 3;
    int kch  = (lane & 7) ^ srow;
    const u16* gbase = isB ? (plane ? Bl : Bh) : (plane ? Al : Ah);
    int rc0 = isB ? col0 : row0;
    const u16* gsrc0 = gbase + (size_t)(rc0 + srow) * 512 + kch * 8;
    u16* lds0 = (isB ? &Bs[0][0][0] : &As[0][0][0]) + plane * 8192;

    f32x16 acc[2][2];
#pragma unroll
    for (int i = 0; i < 2; ++i)
#pragma unroll
        for (int j = 0; j < 2; ++j)
#pragma unroll
            for (int r = 0; r < 16; ++r) acc[i][j][r] = 0.f;

    int ln = lane & 31, l5 = lane >> 5;
    const u16* Afb = &As[0][0][0] + (size_t)(wr * 64 + ln) * 64;
    const u16* Bfb = &Bs[0][0][0] + (size_t)(wc * 64 + ln) * 64;

    for (int k0 = 0; k0 < 512; k0 += 64) {
#pragma unroll
        for (int cc = 0; cc < 16; ++cc)
            gload_lds16(gsrc0 + (size_t)cc * 4096 + k0, lds0 + cc * 512);
        __syncthreads();

#pragma unroll
        for (int ks = 0; ks < 4; ++ks) {
            int pos = ((ks * 2 + l5) ^ (ln & 7)) * 8;
            s16x8 ah0 = *(const s16x8*)(Afb + pos);
            s16x8 ah1 = *(const s16x8*)(Afb + 2048 + pos);
            s16x8 al0 = *(const s16x8*)(Afb + 8192 + pos);
            s16x8 al1 = *(const s16x8*)(Afb + 8192 + 2048 + pos);
#pragma unroll
            for (int j = 0; j < 2; ++j) {
                s16x8 bh = *(const s16x8*)(Bfb + j * 2048 + pos);
                s16x8 bl = *(const s16x8*)(Bfb + 8192 + j * 2048 + pos);
                acc[0][j] = __builtin_amdgcn_mfma_f32_32x32x16_bf16(ah0, bh, acc[0][j], 0, 0, 0);
                acc[1][j] = __builtin_amdgcn_mfma_f32_32x32x16_bf16(ah1, bh, acc[1][j], 0, 0, 0);
                acc[0][j] = __builtin_amdgcn_mfma_f32_32x32x16_bf16(al0, bh, acc[0][j], 0, 0, 0);
                acc[1][j] = __builtin_amdgcn_mfma_f32_32x32x16_bf16(al1, bh, acc[1][j], 0, 0, 0);
                acc[0][j] = __builtin_amdgcn_mfma_f32_32x32x16_bf16(ah0, bl, acc[0][j], 0, 0, 0);
                acc[1][j] = __builtin_amdgcn_mfma_f32_32x32x16_bf16(ah1, bl, acc[1][j], 0, 0, 0);
            }
        }
        __syncthreads();
    }

#pragma unroll
    for (int i = 0; i < 2; ++i)
#pragma unroll
        for (int reg = 0; reg < 16; ++reg) {
            int row = row0 + wr * 64 + i * 32 + l5 * 4 + (reg >> 2) * 8 + (reg & 3);
            float* yp = Y + (size_t)row * 1024 + col0 + wc * 64 + ln;
            yp[0]  = acc[i][0][reg];
            yp[32] = acc[i][1][reg];
        }

#pragma unroll
    for (int j = 0; j < 2; ++j) {
        float s = 0.f, q = 0.f;
#pragma unroll
        for (int i = 0; i < 2; ++i)
#pragma unroll
            for (int reg = 0; reg < 16; ++reg) {
                float v = acc[i][j][reg];
                s += v; q += v * v;
            }
        scs[wr * 2 + l5][wc * 64 + j * 32 + ln] = s;
        sqs[wr * 2 + l5][wc * 64 + j * 32 + ln] = q;
    }
    __syncthreads();
    if (tid < 128) {
        float s = 0.f, q = 0.f;
#pragma unroll
        for (int p = 0; p < 4; ++p) { s += scs[p][tid]; q += sqs[p][tid]; }
        psum[(size_t)bm * 1024 + col0 + tid]   = s;
        psumsq[(size_t)bm * 1024 + col0 + tid] = q;
    }
}

// ---------------- pool partials: BN+act, max & sum over 32-row chunks -----
__global__ __launch_bounds__(256) void pool_part_kernel(
    const float* __restrict__ Y, const float* __restrict__ ss,
    float* __restrict__ pmax, float* __restrict__ psum)
{
    int bid = blockIdx.x;             // 256 = B * 64 chunks
    int b = bid >> 6;
    int n0 = (bid & 63) * 32;
    int t = threadIdx.x;
    int o = t * 4;
    float4 sA = *(const float4*)(ss + o * 2);
    float4 sB = *(const float4*)(ss + o * 2 + 4);
    float4 mx = {-3.4e38f, -3.4e38f, -3.4e38f, -3.4e38f};
    float4 sm = {0.f, 0.f, 0.f, 0.f};
    const float* Yb = Y + ((size_t)b * NN + n0) * 1024 + o;
#pragma unroll 4
    for (int n = 0; n < 32; ++n) {
        float4 v = *(const float4*)(Yb + (size_t)n * 1024);
        float a0 = sA.x * v.x + sA.y; a0 = (a0 > 0.f) ? a0 : NEG * a0;
        float a1 = sA.z * v.y + sA.w; a1 = (a1 > 0.f) ? a1 : NEG * a1;
        float a2 = sB.x * v.z + sB.y; a2 = (a2 > 0.f) ? a2 : NEG * a2;
        float a3 = sB.z * v.w + sB.w; a3 = (a3 > 0.f) ? a3 : NEG * a3;
        mx.x = fmaxf(mx.x, a0); sm.x += a0;
        mx.y = fmaxf(mx.y, a1); sm.y += a1;
        mx.z = fmaxf(mx.z, a2); sm.z += a2;
        mx.w = fmaxf(mx.w, a3); sm.w += a3;
    }
    size_t po = (size_t)bid * 1024 + o;
    *(float4*)(pmax + po) = mx;
    *(float4*)(psum + po) = sm;
}

// ---------------- combine pool partials -> z (B,2048) ----------------
__global__ __launch_bounds__(256) void pool_comb_kernel(
    const float* __restrict__ pmax, const float* __restrict__ psum,
    float* __restrict__ z)
{
    int b = blockIdx.x;               // 4
    int t = threadIdx.x;
    int o = t * 4;
    float4 mx = {-3.4e38f, -3.4e38f, -3.4e38f, -3.4e38f};
    float4 sm = {0.f, 0.f, 0.f, 0.f};
    for (int ch = 0; ch < 64; ++ch) {
        size_t po = ((size_t)(b * 64 + ch)) * 1024 + o;
        float4 m = *(const float4*)(pmax + po);
        float4 s = *(const float4*)(psum + po);
        mx.x = fmaxf(mx.x, m.x); mx.y = fmaxf(mx.y, m.y);
        mx.z = fmaxf(mx.z, m.z); mx.w = fmaxf(mx.w, m.w);
        sm.x += s.x; sm.y += s.y; sm.z += s.z; sm.w += s.w;
    }
    *(float4*)(z + (size_t)b * 2048 + o) = mx;
    float4 mn = {sm.x * (1.f / 2048.f), sm.y * (1.f / 2048.f),
                 sm.z * (1.f / 2048.f), sm.w * (1.f / 2048.f)};
    *(float4*)(z + (size_t)b * 2048 + 1024 + o) = mn;
}

// ---------------- z @ lw1^T + lb1  -> z1 (4,256) ----------------
__global__ __launch_bounds__(64) void gemv1_kernel(
    const float* __restrict__ z, const float* __restrict__ lw1,
    const float* __restrict__ lb1, float* __restrict__ z1)
{
    int o = blockIdx.x;               // 256
    int lane = threadIdx.x;           // 64
    const float* wr = lw1 + (size_t)o * 2048;
    float a0 = 0.f, a1 = 0.f, a2 = 0.f, a3 = 0.f;
    for (int c = lane; c < 2048; c += 64) {
        float w = wr[c];
        a0 += z[c] * w; a1 += z[2048 + c] * w;
        a2 += z[4096 + c] * w; a3 += z[6144 + c] * w;
    }
#pragma unroll
    for (int off = 32; off > 0; off >>= 1) {
        a0 += __shfl_down(a0, off); a1 += __shfl_down(a1, off);
        a2 += __shfl_down(a2, off); a3 += __shfl_down(a3, off);
    }
    if (lane == 0) {
        float bias = lb1[o];
        z1[o] = a0 + bias; z1[256 + o] = a1 + bias;
        z1[512 + o] = a2 + bias; z1[768 + o] = a3 + bias;
    }
}

// ---------------- rest of head: z2, e, cluster q/xd ----------------
__global__ __launch_bounds__(1024) void head2_kernel(
    const float* __restrict__ z1,
    const float* __restrict__ lw2, const float* __restrict__ lb2,
    const float* __restrict__ lw3, const float* __restrict__ lb3,
    const float* __restrict__ cw,
    float* __restrict__ out, float* __restrict__ e_store, int which)
{
    __shared__ float z2s[4][64];
    __shared__ float es[4][10];
    __shared__ float qs[3200];
    __shared__ float dnm[4];
    int t = threadIdx.x;
    if (t < 256) {
        int b = t >> 6, o = t & 63;
        float acc = lb2[o];
        const float* wr = lw2 + (size_t)o * 256;
        const float* zr = z1 + b * 256;
        for (int c = 0; c < 256; ++c) acc += zr[c] * wr[c];
        z2s[b][o] = acc;
    }
    __syncthreads();
    if (t < 40) {
        int b = t / 10, o = t % 10;
        float acc = lb3[o];
        const float* wr = lw3 + o * 64;
        for (int c = 0; c < 64; ++c) acc += z2s[b][c] * wr[c];
        es[b][o] = acc;
        int eoff = (which == 0) ? EOFF0 : EOFF1;
        out[eoff + b * 10 + o] = acc;
        e_store[which * 40 + b * 10 + o] = acc;
    }
    __syncthreads();
    for (int p = t; p < 3200; p += 1024) {
        int b = p / 800, j = p % 800;
        float xd = 0.f;
        const float* cwr = cw + j * 10;
#pragma unroll
        for (int i = 0; i < 10; ++i) { float d = es[b][i] - cwr[i]; xd += d * d; }
        qs[p] = 1.0f / (1.0f + xd);
        if (which == 0) out[XDOFF + p] = xd;
    }
    __syncthreads();
    if (t < 4) {
        float s = 0.f;
        for (int j = 0; j < 800; ++j) s += qs[t * 800 + j];
        dnm[t] = s;
    }
    __syncthreads();
    int qoff = (which == 0) ? QOFF0 : QOFF1;
    for (int p = t; p < 3200; p += 1024) out[qoff + p] = qs[p] / dnm[p / 800];
}

// ---------------- pairwise distance of embeddings ----------------
__global__ void sim_kernel(const float* __restrict__ e_store, float* __restrict__ out)
{
    int t = threadIdx.x;
    if (t < 4) {
        float s = 0.f;
        for (int i = 0; i < 10; ++i) {
            float d = e_store[t * 10 + i] - e_store[40 + t * 10 + i] + 1e-6f;
            s += d * d;
        }
        out[t] = sqrtf(s);
    }
}

extern "C" void kernel_launch(void* const* d_in, const int* in_sizes, int n_in,
                              void* d_out, int out_size, void* d_ws, size_t ws_size,
                              hipStream_t stream)
{
    const float* x1  = (const float*)d_in[0];
    const float* x2  = (const float*)d_in[1];
    const float* w1  = (const float*)d_in[2];
    const float* g1  = (const float*)d_in[3];
    const float* b1  = (const float*)d_in[4];
    const float* w2  = (const float*)d_in[5];
    const float* g2  = (const float*)d_in[6];
    const float* b2  = (const float*)d_in[7];
    const float* w3  = (const float*)d_in[8];
    const float* g3  = (const float*)d_in[9];
    const float* b3  = (const float*)d_in[10];
    const float* w4  = (const float*)d_in[11];
    const float* g4  = (const float*)d_in[12];
    const float* b4  = (const float*)d_in[13];
    const float* w5  = (const float*)d_in[14];
    const float* g5  = (const float*)d_in[15];
    const float* b5  = (const float*)d_in[16];
    const float* lw1 = (const float*)d_in[17];
    const float* lb1 = (const float*)d_in[18];
    const float* lw2 = (const float*)d_in[19];
    const float* lb2 = (const float*)d_in[20];
    const float* lw3 = (const float*)d_in[21];
    const float* lb3 = (const float*)d_in[22];
    const float* cw  = (const float*)d_in[23];
    float* out = (float*)d_out;

    float* ws   = (float*)d_ws;
    float* h512 = ws;                      // B*N*512 = 4194304
    float* G    = h512 + 4194304;          // 2097152 (B*N*256 max)
    float* Hb   = G + 2097152;             // 2097152
    float* ymax = Hb + 2097152;            // 2097152
    float* ymin = ymax + 2097152;          // 2097152
    float* y5   = G;                       // alias: B*N*1024 = 8388608 = G..ymin
    float* Sscr = G;                       // alias: knn scores 2*2048*2048 = 8388608
    float* fcn  = ymin + 2097152;          // 1048576 (B*128*N max)
    float* fnc1 = fcn + 1048576;           // 32768 (B*N*3 padded)
    float* xx   = fnc1 + 32768;            // 8192
    float* psum = xx + 8192;               // 131072 (512*256)
    float* psq  = psum + 131072;           // 131072
    float* ss   = psq + 131072;            // 2048
    float* p5s  = ss + 2048;               // 262144
    float* p5q  = p5s + 262144;            // 262144
    float* ss5  = p5q + 262144;            // 2048
    float* z    = ss5 + 2048;              // 8192
    float* z1   = z + 8192;                // 1024
    float* est  = z1 + 1024;               // 128
    int*   idx  = (int*)(est + 128);       // B*N*20 ints = 163840
    u16*   Ahs  = (u16*)(idx + BB * NN * KK);
    u16*   Als  = Ahs + 4194304;           // 8192*512
    u16*   Bhs  = Als + 4194304;
    u16*   Bls  = Bhs + 524288;            // 1024*512
    u16*   fnc1h = Bls + 524288;           // 8192*32 padded bf16 planes
    u16*   fnc1l = fnc1h + 262144;

    // w5 is constant across `which` -> convert once
    tobf16_b_kernel<<<256, 256, 0, stream>>>(w5, Bhs, Bls);

    for (int which = 0; which < 2; ++which) {
        const float* xin = which ? x2 : x1;
        // ---- layer 1 (C=3 -> 64, choff 0)
        transpose_x_kernel<<<32, 256, 0, stream>>>(xin, fnc1, xx, fnc1h, fnc1l);
        for (int bp = 0; bp < 2; ++bp) {
            knn_dotg_kernel<1><<<256, 512, 0, stream>>>(fnc1h, fnc1l, 32, 0, 2*bp, xx, Sscr);
            knn_selg_kernel<<<1024, 256, 0, stream>>>(Sscr, 2*bp, idx);
        }
        gemm_gh_kernel<3, 64><<<1024, 256, 0, stream>>>(fnc1, 3, 0, w1, G, Hb);
        gather_kernel<64><<<512, 256, 0, stream>>>(G, Hb, idx, ymax, ymin, psum, psq);
        bnscale_kernel<<<64, 256, 0, stream>>>(psum, psq, 512, 64, 163840.f, g1, b1, ss);
        apply_t_kernel<64><<<128, 256, 0, stream>>>(ymax, ymin, ss, 0, h512, fcn, Ahs, Als);
        // ---- layer 2 (C=64 -> 64, choff 64)
        norms_kernel<<<32, 256, 0, stream>>>(h512, 0, 64, xx);
        for (int bp = 0; bp < 2; ++bp) {
            knn_dotg_kernel<2><<<256, 512, 0, stream>>>(Ahs, Als, 512, 0, 2*bp, xx, Sscr);
            knn_selg_kernel<<<1024, 256, 0, stream>>>(Sscr, 2*bp, idx);
        }
        gemm_gh_kernel<64, 64><<<1024, 256, 0, stream>>>(h512, 512, 0, w2, G, Hb);
        gather_kernel<64><<<512, 256, 0, stream>>>(G, Hb, idx, ymax, ymin, psum, psq);
        bnscale_kernel<<<64, 256, 0, stream>>>(psum, psq, 512, 64, 163840.f, g2, b2, ss);
        apply_t_kernel<64><<<128, 256, 0, stream>>>(ymax, ymin, ss, 64, h512, fcn, Ahs, Als);
        // ---- layer 3 (C=64 -> 128, choff 128)
        norms_kernel<<<32, 256, 0, stream>>>(h512, 64, 64, xx);
        for (int bp = 0; bp < 2; ++bp) {
            knn_dotg_kernel<2><<<256, 512, 0, stream>>>(Ahs, Als, 512, 64, 2*bp, xx, Sscr);
            knn_selg_kernel<<<1024, 256, 0, stream>>>(Sscr, 2*bp, idx);
        }
        gemm_gh_kernel<64, 128><<<1024, 256, 0, stream>>>(h512, 512, 64, w3, G, Hb);
        gather_kernel<128><<<512, 256, 0, stream>>>(G, Hb, idx, ymax, ymin, psum, psq);
        bnscale_kernel<<<128, 256, 0, stream>>>(psum, psq, 512, 128, 163840.f, g3, b3, ss);
        apply_t_kernel<128><<<256, 256, 0, stream>>>(ymax, ymin, ss, 128, h512, fcn, Ahs, Als);
        // ---- layer 4 (C=128 -> 256, choff 256)
        norms_kernel<<<32, 256, 0, stream>>>(h512, 128, 128, xx);
        for (int bp = 0; bp < 2; ++bp) {
            knn_dotg_kernel<4><<<256, 512, 0, stream>>>(Ahs, Als, 512, 128, 2*bp, xx, Sscr);
            knn_selg_kernel<<<1024, 256, 0, stream>>>(Sscr, 2*bp, idx);
        }
        gemm_gh_kernel<128, 256><<<1024, 256, 0, stream>>>(h512, 512, 128, w4, G, Hb);
        gather_kernel<256><<<512, 256, 0, stream>>>(G, Hb, idx, ymax, ymin, psum, psq);
        bnscale_kernel<<<256, 256, 0, stream>>>(psum, psq, 512, 256, 163840.f, g4, b4, ss);
        apply_kernel<<<8192, 256, 0, stream>>>(ymax, ymin, ss, 8, 256, h512, Ahs, Als);
        // ---- conv1d (512 -> 1024) via bf16x2-split MFMA + fused stats
        gemm5_mfma_kernel<<<512, 256, 0, stream>>>(Ahs, Als, Bhs, Bls, y5, p5s, p5q);
        bnscale_kernel<<<1024, 256, 0, stream>>>(p5s, p5q, 64, 1024, 8192.f, g5, b5, ss5);
        pool_part_kernel<<<256, 256, 0, stream>>>(y5, ss5, p5s, p5q);
        pool_comb_kernel<<<4, 256, 0, stream>>>(p5s, p5q, z);
        // ---- head
        gemv1_kernel<<<256, 64, 0, stream>>>(z, lw1, lb1, z1);
        head2_kernel<<<1, 1024, 0, stream>>>(z1, lw2, lb2, lw3, lb3, cw, out, est, which);
    }
    sim_kernel<<<1, 64, 0, stream>>>(est, out);
}

// Round 9
// 1069.220 us; speedup vs baseline: 1.2264x; 1.2264x over previous
//
#include <hip/hip_runtime.h>
#include <math.h>

#define BB 4
#define NN 2048
#define KK 20
#define NEG 0.2f

// d_out layout: sim(4) q1(3200) q2(3200) e1(40) e2(40) xd1(3200) = 9684
#define QOFF0 4
#define QOFF1 3204
#define EOFF0 6404
#define EOFF1 6444
#define XDOFF 6484

typedef unsigned short u16;
typedef unsigned int u32;
typedef __attribute__((ext_vector_type(8))) short s16x8;     // 8 bf16 = 4 VGPR
typedef __attribute__((ext_vector_type(4))) float f32x4;     // 16x16 acc
typedef __attribute__((ext_vector_type(16))) float f32x16;   // 32x32 acc
typedef __attribute__((ext_vector_type(8))) u16 u16x8;

// ---------------- fp32 -> bf16 (round-nearest-even) ----------------
__device__ __forceinline__ u16 f2bf(float x) {
    u32 u = __float_as_uint(x);
    u += 0x7FFFu + ((u >> 16) & 1u);
    return (u16)(u >> 16);
}

// ------- transpose x (B,3,N) -> (B,N,3) + norms + padded bf16 planes -------
__global__ __launch_bounds__(256) void transpose_x_kernel(
    const float* __restrict__ x, float* __restrict__ fnc, float* __restrict__ xx,
    u16* __restrict__ fh, u16* __restrict__ fl)
{
    int gid = blockIdx.x * 256 + threadIdx.x;   // B*N = 8192
    int b = gid >> 11, n = gid & 2047;
    float s = 0.f;
    float v[3];
#pragma unroll
    for (int c = 0; c < 3; ++c) {
        v[c] = x[((size_t)b * 3 + c) * NN + n];
        fnc[(size_t)gid * 3 + c] = v[c];
        s += v[c] * v[c];
    }
    xx[gid] = s;
    u16x8 z = {0,0,0,0,0,0,0,0};
    u16x8 h0 = z, l0 = z;
#pragma unroll
    for (int c = 0; c < 3; ++c) {
        u16 hb = f2bf(v[c]);
        h0[c] = hb;
        l0[c] = f2bf(v[c] - __uint_as_float((u32)hb << 16));
    }
    u16* fhp = fh + (size_t)gid * 32;
    u16* flp = fl + (size_t)gid * 32;
    *(u16x8*)(fhp)      = h0; *(u16x8*)(fhp + 8)  = z;
    *(u16x8*)(fhp + 16) = z;  *(u16x8*)(fhp + 24) = z;
    *(u16x8*)(flp)      = l0; *(u16x8*)(flp + 8)  = z;
    *(u16x8*)(flp + 16) = z;  *(u16x8*)(flp + 24) = z;
}

// ---------------- row norms of a h512 channel slice ----------------
__global__ __launch_bounds__(256) void norms_kernel(
    const float* __restrict__ h512, int choff, int C, float* __restrict__ xx)
{
    int gid = blockIdx.x * 256 + threadIdx.x;   // 8192
    const float* p = h512 + (size_t)gid * 512 + choff;
    float s = 0.f;
    for (int c = 0; c < C; ++c) { float v = p[c]; s += v * v; }
    xx[gid] = s;
}

#define NINFV -3.4e38f

// ---- DPP pair-max step: merge sorted pair (a1>=a2) with lane-shifted copy.
// Exactly-once coverage over shr1/2/4/8 + bcast15/31 -> lane 63 holds the
// exact global top-2 of all lanes' pairs.
template<int CTRL>
__device__ __forceinline__ void dmax2(float& a1, float& a2)
{
    int b1i = __builtin_amdgcn_update_dpp(
        __float_as_int(a1), __float_as_int(a1), CTRL, 0xf, 0xf, false);
    int b2i = __builtin_amdgcn_update_dpp(
        __float_as_int(a2), __float_as_int(a2), CTRL, 0xf, 0xf, false);
    float b1 = __int_as_float(b1i), b2 = __int_as_float(b2i);
    float n1 = fmaxf(a1, b1);
    float n2 = fmaxf(fminf(a1, b1), fmaxf(a2, b2));
    a1 = n1; a2 = n2;
}

// ---------------- fused pairwise-dot + top-20 (r6-proven, 97us) ----------
// Dot phase: R8 structure (c-groups of 4, register prefetch, wave-uniform
// center loads). Select: score row LDS-RESIDENT (r4 lesson: reg caching
// spills); per-lane top-4 cache; pair DPP reduction pops TWO winners/round.
template<int C>
__global__ __launch_bounds__(512, 4) void knn_kernel(
    const float* __restrict__ fcn,   // (B,C,N)
    const float* __restrict__ fnc,   // rows of length ncs, center vectors at +choff
    int ncs, int choff,
    const float* __restrict__ xx, int* __restrict__ idxout)
{
    __shared__ float sbuf[8][NN];    // 64 KB
    int tid = threadIdx.x;
    int bid = blockIdx.x;            // 1024
    int b   = bid & 3;
    int n0  = (((bid >> 3) << 1) | ((bid >> 2) & 1)) * 8;   // covers 0..2047 per batch

    const float* fb = fcn + (size_t)b * C * NN;
    const float* xb = xx + b * NN;
    const float* cbase = fnc + (size_t)(b * NN + n0) * ncs + choff;

    float a0[8], a1[8], a2[8], a3[8];
#pragma unroll
    for (int r = 0; r < 8; ++r) { a0[r] = 0.f; a1[r] = 0.f; a2[r] = 0.f; a3[r] = 0.f; }

    const float* fp = fb + 4 * tid;

    if constexpr (C % 4 == 0) {
        float4 buf[4];
#pragma unroll
        for (int q = 0; q < 4; ++q) buf[q] = *(const float4*)(fp + (size_t)q * NN);
        for (int cg = 0; cg < C; cg += 4) {
            float4 nxt[4];
            if (cg + 4 < C) {
#pragma unroll
                for (int q = 0; q < 4; ++q)
                    nxt[q] = *(const float4*)(fp + (size_t)(cg + 4 + q) * NN);
            } else {
#pragma unroll
                for (int q = 0; q < 4; ++q) nxt[q] = buf[q];
            }
            float4 cv[8];
#pragma unroll
            for (int r = 0; r < 8; ++r)
                cv[r] = *(const float4*)(cbase + (size_t)r * ncs + cg);  // uniform -> s_load_dwordx4
#pragma unroll
            for (int r = 0; r < 8; ++r) {
                a0[r] += cv[r].x * buf[0].x; a1[r] += cv[r].x * buf[0].y;
                a2[r] += cv[r].x * buf[0].z; a3[r] += cv[r].x * buf[0].w;
                a0[r] += cv[r].y * buf[1].x; a1[r] += cv[r].y * buf[1].y;
                a2[r] += cv[r].y * buf[1].z; a3[r] += cv[r].y * buf[1].w;
                a0[r] += cv[r].z * buf[2].x; a1[r] += cv[r].z * buf[2].y;
                a2[r] += cv[r].z * buf[2].z; a3[r] += cv[r].z * buf[2].w;
                a0[r] += cv[r].w * buf[3].x; a1[r] += cv[r].w * buf[3].y;
                a2[r] += cv[r].w * buf[3].z; a3[r] += cv[r].w * buf[3].w;
            }
#pragma unroll
            for (int q = 0; q < 4; ++q) buf[q] = nxt[q];
        }
    } else {
        for (int c = 0; c < C; ++c) {
            float cr[8];
#pragma unroll
            for (int r = 0; r < 8; ++r) cr[r] = cbase[(size_t)r * ncs + c];
            float4 v = *(const float4*)(fp + (size_t)c * NN);
#pragma unroll
            for (int r = 0; r < 8; ++r) {
                a0[r] += cr[r] * v.x; a1[r] += cr[r] * v.y;
                a2[r] += cr[r] * v.z; a3[r] += cr[r] * v.w;
            }
        }
    }
    {
        float4 xm = *(const float4*)(xb + 4 * tid);
#pragma unroll
        for (int r = 0; r < 8; ++r) {
            float4 sv = {2.f * a0[r] - xm.x, 2.f * a1[r] - xm.y,
                         2.f * a2[r] - xm.z, 2.f * a3[r] - xm.w};
            *(float4*)&sbuf[r][4 * tid] = sv;
        }
    }
    __syncthreads();

    // ---- select phase: wave w (0..7) handles row w; row stays in LDS
    int w = tid >> 6, lane = tid & 63;
    float* sb = sbuf[w];
    int p = n0 + w;                  // global point index within batch
    int* op = idxout + (size_t)(b * NN + p) * KK;

    if (lane == 0) op[0] = p;        // self is provably the max score
    if (lane == (p & 63)) sb[p] = NINFV;   // kill self column (same-lane RAW)

    // per-lane top-4 cache from LDS (compile-time-indexed scans only)
    float v1 = NINFV, v2 = NINFV, v3 = NINFV, v4 = NINFV;
    int j1 = -1, j2 = -1, j3 = -1, j4 = -1;
#pragma unroll
    for (int j = 0; j < 32; ++j) {
        float vv = sb[lane + (j << 6)];
        if (vv > v1) { v4 = v3; j4 = j3; v3 = v2; j3 = j2; v2 = v1; j2 = j1; v1 = vv; j1 = j; }
        else if (vv > v2) { v4 = v3; j4 = j3; v3 = v2; j3 = j2; v2 = vv; j2 = j; }
        else if (vv > v3) { v4 = v3; j4 = j3; v3 = vv; j3 = j; }
        else if (vv > v4) { v4 = vv; j4 = j; }
    }

    unsigned consumed = 0u;          // bit j set => element j consumed

    for (int it = 1; it < KK; it += 2) {
        float r1 = v1, r2 = v2;
        dmax2<0x111>(r1, r2);        // row_shr:1
        dmax2<0x112>(r1, r2);        // row_shr:2
        dmax2<0x114>(r1, r2);        // row_shr:4
        dmax2<0x118>(r1, r2);        // row_shr:8
        dmax2<0x142>(r1, r2);        // row_bcast:15
        dmax2<0x143>(r1, r2);        // row_bcast:31 -> lane 63 holds top-2
        float m1 = __int_as_float(
            __builtin_amdgcn_readlane(__float_as_int(r1), 63));
        float m2 = __int_as_float(
            __builtin_amdgcn_readlane(__float_as_int(r2), 63));
        unsigned long long k1 = __ballot(v1 == m1);
        if (lane == __ffsll(k1) - 1) {
            op[it] = lane + (j1 << 6);
            consumed |= 1u << j1;
            v1 = v2; j1 = j2; v2 = v3; j2 = j3; v3 = v4; j3 = j4;
            v4 = NINFV; j4 = -1;
        }
        if (it + 1 < KK) {
            // after pop1 the owner's head is its old v2, so a same-lane
            // double win is found by this ballot naturally.
            unsigned long long k2 = __ballot(v1 == m2);
            if (lane == __ffsll(k2) - 1) {
                op[it + 1] = lane + (j1 << 6);
                consumed |= 1u << j1;
                v1 = v2; j1 = j2; v2 = v3; j2 = j3; v3 = v4; j3 = j4;
                v4 = NINFV; j4 = -1;
            }
        }
        // both head entries (v1,v2) must be valid for the next pair round
        if (__any(v2 == NINFV)) {
            if (v2 == NINFV) {       // rare: rebuild top-4 from LDS
                v1 = NINFV; v2 = NINFV; v3 = NINFV; v4 = NINFV;
                j1 = -1; j2 = -1; j3 = -1; j4 = -1;
#pragma unroll
                for (int j = 0; j < 32; ++j) {
                    if (!(consumed & (1u << j))) {
                        float vv = sb[lane + (j << 6)];
                        if (vv > v1) { v4 = v3; j4 = j3; v3 = v2; j3 = j2; v2 = v1; j2 = j1; v1 = vv; j1 = j; }
                        else if (vv > v2) { v4 = v3; j4 = j3; v3 = v2; j3 = j2; v2 = vv; j2 = j; }
                        else if (vv > v3) { v4 = v3; j4 = j3; v3 = vv; j3 = j; }
                        else if (vv > v4) { v4 = vv; j4 = j; }
                    }
                }
            }
        }
    }
}

// ---------------- W -> [W1; W2-W1] K-padded bf16 hi/lo planes -------------
__global__ __launch_bounds__(256) void tobf16_w_kernel(
    const float* __restrict__ W, int C, int COUT, int KP,
    u16* __restrict__ Wh, u16* __restrict__ Wl)
{
    int idx = blockIdx.x * 256 + threadIdx.x;
    if (idx >= 2 * COUT * KP) return;
    int row = idx / KP, c = idx - row * KP;
    int o = (row >= COUT) ? row - COUT : row;
    float val = 0.f;
    if (c < C) {
        float w1 = W[(size_t)o * 2 * C + c];
        val = (row >= COUT) ? (W[(size_t)o * 2 * C + C + c] - w1) : w1;
    }
    u16 hb = f2bf(val);
    Wh[idx] = hb;
    Wl[idx] = f2bf(val - __uint_as_float((u32)hb << 16));
}

// ------------- G = F*W1^T, H = F*(W2-W1)^T via bf16-split MFMA -------------
// 16 F-rows/block, 4 waves stride the 2*COUT output-col 16-tiles. Fragment
// semantics identical to the r7-verified 16x16x32 pattern: A = F rows
// (lane&15 -> row, lane>>4 -> K-chunk), B = Wsplit rows (= output cols),
// D: col=lane&15, row=(lane>>4)*4+reg. W is L2-resident (tiny).
template<int KT, int COUT>
__global__ __launch_bounds__(256) void gemm_gh_mfma_kernel(
    const u16* __restrict__ Fh, const u16* __restrict__ Fl,
    int ncs, int choff,
    const u16* __restrict__ Wh, const u16* __restrict__ Wl,  // (2*COUT, KT*32)
    float* __restrict__ G, float* __restrict__ H)
{
    constexpr int KP = KT * 32;
    constexpr int NT = (2 * COUT) >> 4;
    int tid = threadIdx.x;
    int r0 = blockIdx.x << 4;        // grid = 512
    int wv = tid >> 6, lane = tid & 63;
    int l15 = lane & 15, l4 = lane >> 4;

    const u16* Ah0 = Fh + (size_t)(r0 + l15) * ncs + choff + l4 * 8;
    const u16* Al0 = Fl + (size_t)(r0 + l15) * ncs + choff + l4 * 8;
    s16x8 a_h[KT], a_l[KT];
#pragma unroll
    for (int kt = 0; kt < KT; ++kt) {
        a_h[kt] = *(const s16x8*)(Ah0 + kt * 32);
        a_l[kt] = *(const s16x8*)(Al0 + kt * 32);
    }

    for (int t = wv; t < NT; t += 4) {
        int c0 = t << 4;
        const u16* Bh0 = Wh + (size_t)(c0 + l15) * KP + l4 * 8;
        const u16* Bl0 = Wl + (size_t)(c0 + l15) * KP + l4 * 8;
        f32x4 acc;
#pragma unroll
        for (int i = 0; i < 4; ++i) acc[i] = 0.f;
#pragma unroll
        for (int kt = 0; kt < KT; ++kt) {
            s16x8 bh = *(const s16x8*)(Bh0 + kt * 32);
            s16x8 bl = *(const s16x8*)(Bl0 + kt * 32);
            acc = __builtin_amdgcn_mfma_f32_16x16x32_bf16(a_h[kt], bh, acc, 0, 0, 0);
            acc = __builtin_amdgcn_mfma_f32_16x16x32_bf16(a_l[kt], bh, acc, 0, 0, 0);
            acc = __builtin_amdgcn_mfma_f32_16x16x32_bf16(a_h[kt], bl, acc, 0, 0, 0);
        }
        int col = c0 + l15;
        float* dst = (col < COUT) ? G : H;
        int cc = (col < COUT) ? col : col - COUT;
#pragma unroll
        for (int i = 0; i < 4; ++i)
            dst[(size_t)(r0 + l4 * 4 + i) * COUT + cc] = acc[i];
    }
}

// ---------------- gather y=G[m]+H[n]; max/min over k; BN stat partials -----
template<int COUT>
__global__ __launch_bounds__(256) void gather_kernel(
    const float* __restrict__ G, const float* __restrict__ H,
    const int* __restrict__ idx,
    float* __restrict__ ymax, float* __restrict__ ymin,
    float* __restrict__ psum, float* __restrict__ psumsq)
{
    constexpr int RPI = 256 / COUT;
    constexpr int NITER = 16 / RPI;
    int tid = threadIdx.x;
    int o = tid % COUT;
    int rsub = tid / COUT;
    int row0 = blockIdx.x * 16;       // grid = 512
    float s = 0.f, s2 = 0.f;
    for (int it = 0; it < NITER; ++it) {
        int r = row0 + it * RPI + rsub;
        int b = r >> 11;
        float h = H[(size_t)r * COUT + o];
        const int* ip = idx + (size_t)r * KK;
        float mx = -3.4e38f, mn = 3.4e38f;
#pragma unroll
        for (int j = 0; j < KK; ++j) {
            int m = ip[j];
            float g = G[((size_t)(b << 11) + m) * COUT + o];
            float y = g + h;
            mx = fmaxf(mx, y); mn = fminf(mn, y);
            s += y; s2 += y * y;
        }
        ymax[(size_t)r * COUT + o] = mx;
        ymin[(size_t)r * COUT + o] = mn;
    }
    __shared__ float ls[256], ls2[256];
    ls[tid] = s; ls2[tid] = s2;
    __syncthreads();
    for (int st = 128; st >= COUT; st >>= 1) {
        if (tid < st) { ls[tid] += ls[tid + st]; ls2[tid] += ls2[tid + st]; }
        __syncthreads();
    }
    if (tid < COUT) {
        psum[(size_t)blockIdx.x * COUT + tid]   = ls[tid];
        psumsq[(size_t)blockIdx.x * COUT + tid] = ls2[tid];
    }
}

// ---------------- finalize BN scale/shift: one block per channel ----------
__global__ __launch_bounds__(256) void bnscale_kernel(
    const float* __restrict__ psum, const float* __restrict__ psumsq,
    int nblk, int cout, float cnt,
    const float* __restrict__ gw, const float* __restrict__ bw,
    float* __restrict__ ss)
{
    int o = blockIdx.x;               // grid = cout
    int t = threadIdx.x;
    float s = 0.f, s2 = 0.f;
    for (int i = t; i < nblk; i += 256) {
        s  += psum[(size_t)i * cout + o];
        s2 += psumsq[(size_t)i * cout + o];
    }
    __shared__ float ls[256], ls2[256];
    ls[t] = s; ls2[t] = s2;
    __syncthreads();
    for (int st = 128; st > 0; st >>= 1) {
        if (t < st) { ls[t] += ls[t + st]; ls2[t] += ls2[t + st]; }
        __syncthreads();
    }
    if (t == 0) {
        float m = ls[0] / cnt;
        float v = ls2[0] / cnt - m * m;
        float sc = gw[o] / sqrtf(v + 1e-5f);
        float sh = bw[o] - m * sc;
        ss[o * 2] = sc; ss[o * 2 + 1] = sh;
    }
}

// ------- BN+LeakyReLU on max/min, elementwise + bf16 hi/lo emission -------
__global__ __launch_bounds__(256) void apply_kernel(
    const float* __restrict__ ymax, const float* __restrict__ ymin,
    const float* __restrict__ ss, int coutShift, int choff,
    float* __restrict__ h512, u16* __restrict__ Ah, u16* __restrict__ Al)
{
    size_t gid = (size_t)blockIdx.x * 256 + threadIdx.x;
    int o = (int)(gid & ((1u << coutShift) - 1));
    size_t r = gid >> coutShift;
    float sc = ss[o * 2], sh = ss[o * 2 + 1];
    float v = (sc >= 0.f) ? ymax[gid] : ymin[gid];
    float a = sc * v + sh;
    float act = (a > 0.f) ? a : NEG * a;
    size_t hidx = r * 512 + choff + o;
    h512[hidx] = act;
    u16 hb = f2bf(act);
    Ah[hidx] = hb;
    Al[hidx] = f2bf(act - __uint_as_float((u32)hb << 16));
}

// ---- BN+LeakyReLU + coalesced transposed fcn write + bf16 hi/lo ----------
template<int CO>
__global__ __launch_bounds__(256) void apply_t_kernel(
    const float* __restrict__ ymax, const float* __restrict__ ymin,
    const float* __restrict__ ss, int choff,
    float* __restrict__ h512, float* __restrict__ fcn,
    u16* __restrict__ Ah, u16* __restrict__ Al)
{
    constexpr int TILES_O = CO >> 6;
    __shared__ float tile[64][65];
    int tr = blockIdx.x / TILES_O;    // row tile 0..127
    int to = blockIdx.x % TILES_O;
    int r0 = tr * 64, o0 = to * 64;
    int t = threadIdx.x;
    int lr = t >> 6;                  // 0..3
    int lo = t & 63;
    int o = o0 + lo;
    float sc = ss[o * 2], sh = ss[o * 2 + 1];
#pragma unroll
    for (int rr = 0; rr < 64; rr += 4) {
        int r = r0 + rr + lr;
        size_t gid = (size_t)r * CO + o;
        float v = (sc >= 0.f) ? ymax[gid] : ymin[gid];
        float a = sc * v + sh;
        float act = (a > 0.f) ? a : NEG * a;
        size_t hidx = (size_t)r * 512 + choff + o;
        h512[hidx] = act;
        u16 hb = f2bf(act);
        Ah[hidx] = hb;
        Al[hidx] = f2bf(act - __uint_as_float((u32)hb << 16));
        tile[rr + lr][lo] = act;
    }
    __syncthreads();
    int b = r0 >> 11;
    int n0 = r0 & 2047;
#pragma unroll
    for (int oo = 0; oo < 64; oo += 4) {
        fcn[((size_t)(b * CO + o0 + oo + lr)) * NN + n0 + lo] = tile[lo][oo + lr];
    }
}

// ---------------- fp32 -> (hi, lo) bf16 split for w5 only ----------------
__global__ __launch_bounds__(256) void tobf16_b_kernel(
    const float* __restrict__ Bm, u16* __restrict__ Bh, u16* __restrict__ Bl)
{
    int gid = blockIdx.x * 256 + threadIdx.x;   // 65536 (1024*512/8)
    size_t off = (size_t)gid * 8;
    float4 v0 = *(const float4*)(Bm + off);
    float4 v1 = *(const float4*)(Bm + off + 4);
    float x[8] = {v0.x, v0.y, v0.z, v0.w, v1.x, v1.y, v1.z, v1.w};
    u16x8 h, l;
#pragma unroll
    for (int j = 0; j < 8; ++j) {
        u16 hb = f2bf(x[j]);
        h[j] = hb;
        l[j] = f2bf(x[j] - __uint_as_float((u32)hb << 16));
    }
    *(u16x8*)(Bh + off) = h;
    *(u16x8*)(Bl + off) = l;
}

// ============ conv1d GEMM via bf16x2-split MFMA (32x32x16) ============
__device__ __forceinline__ void gload_lds16(const void* g, void* l) {
    __builtin_amdgcn_global_load_lds(
        (const __attribute__((address_space(1))) void*)g,
        (__attribute__((address_space(3))) void*)l, 16, 0, 0);
}

__global__ __launch_bounds__(256) void gemm5_mfma_kernel(
    const u16* __restrict__ Ah, const u16* __restrict__ Al,
    const u16* __restrict__ Bh, const u16* __restrict__ Bl,
    float* __restrict__ Y, float* __restrict__ psum, float* __restrict__ psumsq)
{
    __shared__ u16 As[2][128][64];   // [plane][row][k] 32 KB
    __shared__ u16 Bs[2][128][64];   // 32 KB
    __shared__ float scs[4][128];
    __shared__ float sqs[4][128];

    int tid = threadIdx.x;
    int bm = blockIdx.x & 63, bn = blockIdx.x >> 6;
    int row0 = bm * 128, col0 = bn * 128;
    int w = tid >> 6, lane = tid & 63;
    int wr = w >> 1, wc = w & 1;

    int isB = w >> 1, plane = w & 1;
    int srow = lane >> 3;
    int kch  = (lane & 7) ^ srow;
    const u16* gbase = isB ? (plane ? Bl : Bh) : (plane ? Al : Ah);
    int rc0 = isB ? col0 : row0;
    const u16* gsrc0 = gbase + (size_t)(rc0 + srow) * 512 + kch * 8;
    u16* lds0 = (isB ? &Bs[0][0][0] : &As[0][0][0]) + plane * 8192;

    f32x16 acc[2][2];
#pragma unroll
    for (int i = 0; i < 2; ++i)
#pragma unroll
        for (int j = 0; j < 2; ++j)
#pragma unroll
            for (int r = 0; r < 16; ++r) acc[i][j][r] = 0.f;

    int ln = lane & 31, l5 = lane >> 5;
    const u16* Afb = &As[0][0][0] + (size_t)(wr * 64 + ln) * 64;
    const u16* Bfb = &Bs[0][0][0] + (size_t)(wc * 64 + ln) * 64;

    for (int k0 = 0; k0 < 512; k0 += 64) {
#pragma unroll
        for (int cc = 0; cc < 16; ++cc)
            gload_lds16(gsrc0 + (size_t)cc * 4096 + k0, lds0 + cc * 512);
        __syncthreads();

#pragma unroll
        for (int ks = 0; ks < 4; ++ks) {
            int pos = ((ks * 2 + l5) ^ (ln & 7)) * 8;
            s16x8 ah0 = *(const s16x8*)(Afb + pos);
            s16x8 ah1 = *(const s16x8*)(Afb + 2048 + pos);
            s16x8 al0 = *(const s16x8*)(Afb + 8192 + pos);
            s16x8 al1 = *(const s16x8*)(Afb + 8192 + 2048 + pos);
#pragma unroll
            for (int j = 0; j < 2; ++j) {
                s16x8 bh = *(const s16x8*)(Bfb + j * 2048 + pos);
                s16x8 bl = *(const s16x8*)(Bfb + 8192 + j * 2048 + pos);
                acc[0][j] = __builtin_amdgcn_mfma_f32_32x32x16_bf16(ah0, bh, acc[0][j], 0, 0, 0);
                acc[1][j] = __builtin_amdgcn_mfma_f32_32x32x16_bf16(ah1, bh, acc[1][j], 0, 0, 0);
                acc[0][j] = __builtin_amdgcn_mfma_f32_32x32x16_bf16(al0, bh, acc[0][j], 0, 0, 0);
                acc[1][j] = __builtin_amdgcn_mfma_f32_32x32x16_bf16(al1, bh, acc[1][j], 0, 0, 0);
                acc[0][j] = __builtin_amdgcn_mfma_f32_32x32x16_bf16(ah0, bl, acc[0][j], 0, 0, 0);
                acc[1][j] = __builtin_amdgcn_mfma_f32_32x32x16_bf16(ah1, bl, acc[1][j], 0, 0, 0);
            }
        }
        __syncthreads();
    }

#pragma unroll
    for (int i = 0; i < 2; ++i)
#pragma unroll
        for (int reg = 0; reg < 16; ++reg) {
            int row = row0 + wr * 64 + i * 32 + l5 * 4 + (reg >> 2) * 8 + (reg & 3);
            float* yp = Y + (size_t)row * 1024 + col0 + wc * 64 + ln;
            yp[0]  = acc[i][0][reg];
            yp[32] = acc[i][1][reg];
        }

#pragma unroll
    for (int j = 0; j < 2; ++j) {
        float s = 0.f, q = 0.f;
#pragma unroll
        for (int i = 0; i < 2; ++i)
#pragma unroll
            for (int reg = 0; reg < 16; ++reg) {
                float v = acc[i][j][reg];
                s += v; q += v * v;
            }
        scs[wr * 2 + l5][wc * 64 + j * 32 + ln] = s;
        sqs[wr * 2 + l5][wc * 64 + j * 32 + ln] = q;
    }
    __syncthreads();
    if (tid < 128) {
        float s = 0.f, q = 0.f;
#pragma unroll
        for (int p = 0; p < 4; ++p) { s += scs[p][tid]; q += sqs[p][tid]; }
        psum[(size_t)bm * 1024 + col0 + tid]   = s;
        psumsq[(size_t)bm * 1024 + col0 + tid] = q;
    }
}

// ---------------- pool partials: BN+act, max & sum over 32-row chunks -----
__global__ __launch_bounds__(256) void pool_part_kernel(
    const float* __restrict__ Y, const float* __restrict__ ss,
    float* __restrict__ pmax, float* __restrict__ psum)
{
    int bid = blockIdx.x;             // 256 = B * 64 chunks
    int b = bid >> 6;
    int n0 = (bid & 63) * 32;
    int t = threadIdx.x;
    int o = t * 4;
    float4 sA = *(const float4*)(ss + o * 2);
    float4 sB = *(const float4*)(ss + o * 2 + 4);
    float4 mx = {-3.4e38f, -3.4e38f, -3.4e38f, -3.4e38f};
    float4 sm = {0.f, 0.f, 0.f, 0.f};
    const float* Yb = Y + ((size_t)b * NN + n0) * 1024 + o;
#pragma unroll 4
    for (int n = 0; n < 32; ++n) {
        float4 v = *(const float4*)(Yb + (size_t)n * 1024);
        float a0 = sA.x * v.x + sA.y; a0 = (a0 > 0.f) ? a0 : NEG * a0;
        float a1 = sA.z * v.y + sA.w; a1 = (a1 > 0.f) ? a1 : NEG * a1;
        float a2 = sB.x * v.z + sB.y; a2 = (a2 > 0.f) ? a2 : NEG * a2;
        float a3 = sB.z * v.w + sB.w; a3 = (a3 > 0.f) ? a3 : NEG * a3;
        mx.x = fmaxf(mx.x, a0); sm.x += a0;
        mx.y = fmaxf(mx.y, a1); sm.y += a1;
        mx.z = fmaxf(mx.z, a2); sm.z += a2;
        mx.w = fmaxf(mx.w, a3); sm.w += a3;
    }
    size_t po = (size_t)bid * 1024 + o;
    *(float4*)(pmax + po) = mx;
    *(float4*)(psum + po) = sm;
}

// ---------------- combine pool partials -> z (B,2048) ----------------
__global__ __launch_bounds__(256) void pool_comb_kernel(
    const float* __restrict__ pmax, const float* __restrict__ psum,
    float* __restrict__ z)
{
    int b = blockIdx.x;               // 4
    int t = threadIdx.x;
    int o = t * 4;
    float4 mx = {-3.4e38f, -3.4e38f, -3.4e38f, -3.4e38f};
    float4 sm = {0.f, 0.f, 0.f, 0.f};
    for (int ch = 0; ch < 64; ++ch) {
        size_t po = ((size_t)(b * 64 + ch)) * 1024 + o;
        float4 m = *(const float4*)(pmax + po);
        float4 s = *(const float4*)(psum + po);
        mx.x = fmaxf(mx.x, m.x); mx.y = fmaxf(mx.y, m.y);
        mx.z = fmaxf(mx.z, m.z); mx.w = fmaxf(mx.w, m.w);
        sm.x += s.x; sm.y += s.y; sm.z += s.z; sm.w += s.w;
    }
    *(float4*)(z + (size_t)b * 2048 + o) = mx;
    float4 mn = {sm.x * (1.f / 2048.f), sm.y * (1.f / 2048.f),
                 sm.z * (1.f / 2048.f), sm.w * (1.f / 2048.f)};
    *(float4*)(z + (size_t)b * 2048 + 1024 + o) = mn;
}

// ---------------- z @ lw1^T + lb1  -> z1 (4,256) ----------------
__global__ __launch_bounds__(64) void gemv1_kernel(
    const float* __restrict__ z, const float* __restrict__ lw1,
    const float* __restrict__ lb1, float* __restrict__ z1)
{
    int o = blockIdx.x;               // 256
    int lane = threadIdx.x;           // 64
    const float* wr = lw1 + (size_t)o * 2048;
    float a0 = 0.f, a1 = 0.f, a2 = 0.f, a3 = 0.f;
    for (int c = lane; c < 2048; c += 64) {
        float w = wr[c];
        a0 += z[c] * w; a1 += z[2048 + c] * w;
        a2 += z[4096 + c] * w; a3 += z[6144 + c] * w;
    }
#pragma unroll
    for (int off = 32; off > 0; off >>= 1) {
        a0 += __shfl_down(a0, off); a1 += __shfl_down(a1, off);
        a2 += __shfl_down(a2, off); a3 += __shfl_down(a3, off);
    }
    if (lane == 0) {
        float bias = lb1[o];
        z1[o] = a0 + bias; z1[256 + o] = a1 + bias;
        z1[512 + o] = a2 + bias; z1[768 + o] = a3 + bias;
    }
}

// ---------------- rest of head: z2, e, cluster q/xd ----------------
__global__ __launch_bounds__(1024) void head2_kernel(
    const float* __restrict__ z1,
    const float* __restrict__ lw2, const float* __restrict__ lb2,
    const float* __restrict__ lw3, const float* __restrict__ lb3,
    const float* __restrict__ cw,
    float* __restrict__ out, float* __restrict__ e_store, int which)
{
    __shared__ float z2s[4][64];
    __shared__ float es[4][10];
    __shared__ float qs[3200];
    __shared__ float dnm[4];
    int t = threadIdx.x;
    if (t < 256) {
        int b = t >> 6, o = t & 63;
        float acc = lb2[o];
        const float* wr = lw2 + (size_t)o * 256;
        const float* zr = z1 + b * 256;
        for (int c = 0; c < 256; ++c) acc += zr[c] * wr[c];
        z2s[b][o] = acc;
    }
    __syncthreads();
    if (t < 40) {
        int b = t / 10, o = t % 10;
        float acc = lb3[o];
        const float* wr = lw3 + o * 64;
        for (int c = 0; c < 64; ++c) acc += z2s[b][c] * wr[c];
        es[b][o] = acc;
        int eoff = (which == 0) ? EOFF0 : EOFF1;
        out[eoff + b * 10 + o] = acc;
        e_store[which * 40 + b * 10 + o] = acc;
    }
    __syncthreads();
    for (int p = t; p < 3200; p += 1024) {
        int b = p / 800, j = p % 800;
        float xd = 0.f;
        const float* cwr = cw + j * 10;
#pragma unroll
        for (int i = 0; i < 10; ++i) { float d = es[b][i] - cwr[i]; xd += d * d; }
        qs[p] = 1.0f / (1.0f + xd);
        if (which == 0) out[XDOFF + p] = xd;
    }
    __syncthreads();
    if (t < 4) {
        float s = 0.f;
        for (int j = 0; j < 800; ++j) s += qs[t * 800 + j];
        dnm[t] = s;
    }
    __syncthreads();
    int qoff = (which == 0) ? QOFF0 : QOFF1;
    for (int p = t; p < 3200; p += 1024) out[qoff + p] = qs[p] / dnm[p / 800];
}

// ---------------- pairwise distance of embeddings ----------------
__global__ void sim_kernel(const float* __restrict__ e_store, float* __restrict__ out)
{
    int t = threadIdx.x;
    if (t < 4) {
        float s = 0.f;
        for (int i = 0; i < 10; ++i) {
            float d = e_store[t * 10 + i] - e_store[40 + t * 10 + i] + 1e-6f;
            s += d * d;
        }
        out[t] = sqrtf(s);
    }
}

extern "C" void kernel_launch(void* const* d_in, const int* in_sizes, int n_in,
                              void* d_out, int out_size, void* d_ws, size_t ws_size,
                              hipStream_t stream)
{
    const float* x1  = (const float*)d_in[0];
    const float* x2  = (const float*)d_in[1];
    const float* w1  = (const float*)d_in[2];
    const float* g1  = (const float*)d_in[3];
    const float* b1  = (const float*)d_in[4];
    const float* w2  = (const float*)d_in[5];
    const float* g2  = (const float*)d_in[6];
    const float* b2  = (const float*)d_in[7];
    const float* w3  = (const float*)d_in[8];
    const float* g3  = (const float*)d_in[9];
    const float* b3  = (const float*)d_in[10];
    const float* w4  = (const float*)d_in[11];
    const float* g4  = (const float*)d_in[12];
    const float* b4  = (const float*)d_in[13];
    const float* w5  = (const float*)d_in[14];
    const float* g5  = (const float*)d_in[15];
    const float* b5  = (const float*)d_in[16];
    const float* lw1 = (const float*)d_in[17];
    const float* lb1 = (const float*)d_in[18];
    const float* lw2 = (const float*)d_in[19];
    const float* lb2 = (const float*)d_in[20];
    const float* lw3 = (const float*)d_in[21];
    const float* lb3 = (const float*)d_in[22];
    const float* cw  = (const float*)d_in[23];
    float* out = (float*)d_out;

    float* ws   = (float*)d_ws;
    float* h512 = ws;                      // B*N*512 = 4194304
    float* G    = h512 + 4194304;          // 2097152 (B*N*256 max)
    float* Hb   = G + 2097152;             // 2097152
    float* ymax = Hb + 2097152;            // 2097152
    float* ymin = ymax + 2097152;          // 2097152
    float* y5   = G;                       // alias: B*N*1024 = 8388608 = G..ymin
    float* fcn  = ymin + 2097152;          // 1048576 (B*128*N max)
    float* fnc1 = fcn + 1048576;           // 32768 (B*N*3 padded)
    float* xx   = fnc1 + 32768;            // 8192
    float* psum = xx + 8192;               // 131072 (512*256)
    float* psq  = psum + 131072;           // 131072
    float* ss   = psq + 131072;            // 2048
    float* p5s  = ss + 2048;               // 262144
    float* p5q  = p5s + 262144;            // 262144
    float* ss5  = p5q + 262144;            // 2048
    float* z    = ss5 + 2048;              // 8192
    float* z1   = z + 8192;                // 1024
    float* est  = z1 + 1024;               // 128
    int*   idx  = (int*)(est + 128);       // B*N*20 ints = 163840
    u16*   Ahs  = (u16*)(idx + BB * NN * KK);
    u16*   Als  = Ahs + 4194304;           // 8192*512
    u16*   Bhs  = Als + 4194304;
    u16*   Bls  = Bhs + 524288;            // 1024*512
    u16*   fnc1h = Bls + 524288;           // 8192*32 padded bf16 planes
    u16*   fnc1l = fnc1h + 262144;
    u16*   Wh   = fnc1l + 262144;          // [W1;W2-W1] planes: 94208 u16
    u16*   Wl   = Wh + 98304;

    // constant-across-which conversions, hoisted
    tobf16_b_kernel<<<256, 256, 0, stream>>>(w5, Bhs, Bls);
    tobf16_w_kernel<<<16,  256, 0, stream>>>(w1, 3,   64,  32,  Wh,         Wl);
    tobf16_w_kernel<<<32,  256, 0, stream>>>(w2, 64,  64,  64,  Wh + 4096,  Wl + 4096);
    tobf16_w_kernel<<<64,  256, 0, stream>>>(w3, 64,  128, 64,  Wh + 12288, Wl + 12288);
    tobf16_w_kernel<<<256, 256, 0, stream>>>(w4, 128, 256, 128, Wh + 28672, Wl + 28672);

    for (int which = 0; which < 2; ++which) {
        const float* xin = which ? x2 : x1;
        // ---- layer 1 (C=3 -> 64, choff 0)
        transpose_x_kernel<<<32, 256, 0, stream>>>(xin, fnc1, xx, fnc1h, fnc1l);
        knn_kernel<3><<<1024, 512, 0, stream>>>(xin, fnc1, 3, 0, xx, idx);
        gemm_gh_mfma_kernel<1, 64><<<512, 256, 0, stream>>>(fnc1h, fnc1l, 32, 0, Wh, Wl, G, Hb);
        gather_kernel<64><<<512, 256, 0, stream>>>(G, Hb, idx, ymax, ymin, psum, psq);
        bnscale_kernel<<<64, 256, 0, stream>>>(psum, psq, 512, 64, 163840.f, g1, b1, ss);
        apply_t_kernel<64><<<128, 256, 0, stream>>>(ymax, ymin, ss, 0, h512, fcn, Ahs, Als);
        // ---- layer 2 (C=64 -> 64, choff 64)
        norms_kernel<<<32, 256, 0, stream>>>(h512, 0, 64, xx);
        knn_kernel<64><<<1024, 512, 0, stream>>>(fcn, h512, 512, 0, xx, idx);
        gemm_gh_mfma_kernel<2, 64><<<512, 256, 0, stream>>>(Ahs, Als, 512, 0, Wh + 4096, Wl + 4096, G, Hb);
        gather_kernel<64><<<512, 256, 0, stream>>>(G, Hb, idx, ymax, ymin, psum, psq);
        bnscale_kernel<<<64, 256, 0, stream>>>(psum, psq, 512, 64, 163840.f, g2, b2, ss);
        apply_t_kernel<64><<<128, 256, 0, stream>>>(ymax, ymin, ss, 64, h512, fcn, Ahs, Als);
        // ---- layer 3 (C=64 -> 128, choff 128)
        norms_kernel<<<32, 256, 0, stream>>>(h512, 64, 64, xx);
        knn_kernel<64><<<1024, 512, 0, stream>>>(fcn, h512, 512, 64, xx, idx);
        gemm_gh_mfma_kernel<2, 128><<<512, 256, 0, stream>>>(Ahs, Als, 512, 64, Wh + 12288, Wl + 12288, G, Hb);
        gather_kernel<128><<<512, 256, 0, stream>>>(G, Hb, idx, ymax, ymin, psum, psq);
        bnscale_kernel<<<128, 256, 0, stream>>>(psum, psq, 512, 128, 163840.f, g3, b3, ss);
        apply_t_kernel<128><<<256, 256, 0, stream>>>(ymax, ymin, ss, 128, h512, fcn, Ahs, Als);
        // ---- layer 4 (C=128 -> 256, choff 256)
        norms_kernel<<<32, 256, 0, stream>>>(h512, 128, 128, xx);
        knn_kernel<128><<<1024, 512, 0, stream>>>(fcn, h512, 512, 128, xx, idx);
        gemm_gh_mfma_kernel<4, 256><<<512, 256, 0, stream>>>(Ahs, Als, 512, 128, Wh + 28672, Wl + 28672, G, Hb);
        gather_kernel<256><<<512, 256, 0, stream>>>(G, Hb, idx, ymax, ymin, psum, psq);
        bnscale_kernel<<<256, 256, 0, stream>>>(psum, psq, 512, 256, 163840.f, g4, b4, ss);
        apply_kernel<<<8192, 256, 0, stream>>>(ymax, ymin, ss, 8, 256, h512, Ahs, Als);
        // ---- conv1d (512 -> 1024) via bf16x2-split MFMA + fused stats
        gemm5_mfma_kernel<<<512, 256, 0, stream>>>(Ahs, Als, Bhs, Bls, y5, p5s, p5q);
        bnscale_kernel<<<1024, 256, 0, stream>>>(p5s, p5q, 64, 1024, 8192.f, g5, b5, ss5);
        pool_part_kernel<<<256, 256, 0, stream>>>(y5, ss5, p5s, p5q);
        pool_comb_kernel<<<4, 256, 0, stream>>>(p5s, p5q, z);
        // ---- head
        gemv1_kernel<<<256, 64, 0, stream>>>(z, lw1, lb1, z1);
        head2_kernel<<<1, 1024, 0, stream>>>(z1, lw2, lb2, lw3, lb3, cw, out, est, which);
    }
    sim_kernel<<<1, 64, 0, stream>>>(est, out);
}